// Round 4
// baseline (222.549 us; speedup 1.0000x reference)
//
#include <hip/hip_runtime.h>

// Problem constants
#define NB     16
#define LATD   512
#define FIN_C  128
#define FOUT_C 128
#define KK     3
#define HW     64
#define KSZ    147456      // FOUT*FIN*K*K
#define NROWS  147584      // KSZ + FOUT (bias rows)

// padded channel-last x: [b][66][66][128]
#define XPAD   66
#define XT_BE  ((size_t)XPAD * XPAD * FIN_C)  // 557568 elems per b

// workspace layout (bytes)
#define AFH_OFF  ((size_t)0)
#define AF_BYTES ((size_t)NB * KSZ * 2)          // 4,718,592
#define AFL_OFF  (AFH_OFF + AF_BYTES)
#define XTH_OFF  (AFL_OFF + AF_BYTES)            // 9,437,184
#define XT_BYTES ((size_t)NB * XT_BE * 2)        // 17,842,176
#define XTL_OFF  (XTH_OFF + XT_BYTES)
#define BIAS_OFF (XTL_OFF + XT_BYTES)            // 45,121,536
#define WS_NEED  (BIAS_OFF + (size_t)NB * FOUT_C * 4)

typedef __attribute__((ext_vector_type(8))) short bf16x8;
typedef __attribute__((ext_vector_type(4))) float f32x4;
typedef __attribute__((ext_vector_type(2))) float f32x2;

#define GLOAD16(gp, lp)                                                        \
  __builtin_amdgcn_global_load_lds(                                            \
      (const __attribute__((address_space(1))) void*)(gp),                     \
      (__attribute__((address_space(3))) void*)(lp), 16, 0, 0)

// Explicit drain of this wave's outstanding global_load_lds BEFORE the
// barrier.  __syncthreads() alone is insufficient: the compiler may sink the
// per-wave vmcnt wait past s_barrier (legal by single-thread alias analysis,
// wrong cross-wave for DMA'd LDS granules consumed by OTHER waves).
#define VMCNT0_BARRIER()                                                       \
  do {                                                                         \
    asm volatile("s_waitcnt vmcnt(0)" ::: "memory");                           \
    __syncthreads();                                                           \
  } while (0)

__device__ __forceinline__ unsigned short f2bf(float f) {
  unsigned u = __builtin_bit_cast(unsigned, f);
  u += 0x7fffu + ((u >> 16) & 1u);       // RNE
  return (unsigned short)(u >> 16);
}
__device__ __forceinline__ float bf2f(unsigned short h) {
  return __builtin_bit_cast(float, ((unsigned)h) << 16);
}

// Af linear index d -> W row index n (A-fragment order for 16x16x32 MFMA)
__device__ __forceinline__ int dton(int d) {
  int e = d & 7, l = (d >> 3) & 63, mt = (d >> 9) & 7;
  int fib = (d >> 12) & 3, t = d >> 14;
  int fo = mt * 16 + (l & 15);
  int fi = fib * 32 + (l >> 4) * 8 + e;
  return fo * (FIN_C * KK * KK) + fi * (KK * KK) + t;
}

// ---------------------------------------------------------------------------
// Kernel 1: hyper GEMM.  ks[n][b] -> kern as bf16 hi/lo in MFMA A-frag order.
// 2 columns/thread + packed f32x2 FMA (v_pk_fma_f32): VALU floor ~31 us,
// HBM floor ~48 us (302 MB of W).  lat staged in LDS (broadcast b128 reads).
// ---------------------------------------------------------------------------
__global__ __launch_bounds__(256) void hyper_gemm2(
    const float* __restrict__ lat, const float* __restrict__ W,
    const float* __restrict__ bvec, unsigned short* __restrict__ Afh,
    unsigned short* __restrict__ Afl, float* __restrict__ bias_ws) {
  __shared__ float lds_lat[NB * LATD];   // 32 KB
  const int tid = threadIdx.x;
#pragma unroll
  for (int r = 0; r < 8; ++r) {
    int i = tid + r * 256;
    *(float4*)&lds_lat[i * 4] = *(const float4*)(lat + i * 4);
  }
  __syncthreads();

  if (blockIdx.x == 288) {               // bias rows
    if (tid >= FOUT_C) return;
    int n = KSZ + tid;
    const float4* w4 = (const float4*)(W + (size_t)n * LATD);
    float4 a4[NB] = {};
#pragma unroll 2
    for (int k4 = 0; k4 < LATD / 4; ++k4) {
      float4 wv = w4[k4];
#pragma unroll
      for (int b = 0; b < NB; ++b) {
        float4 lv = *(const float4*)&lds_lat[b * LATD + k4 * 4];
        a4[b].x += wv.x * lv.x; a4[b].y += wv.y * lv.y;
        a4[b].z += wv.z * lv.z; a4[b].w += wv.w * lv.w;
      }
    }
    float bv = bvec[n];
#pragma unroll
    for (int b = 0; b < NB; ++b)
      bias_ws[b * FOUT_C + tid] = a4[b].x + a4[b].y + a4[b].z + a4[b].w + bv;
    return;
  }

  const int d0 = blockIdx.x * 512 + tid;   // columns d0 and d0+256
  const int d1 = d0 + 256;
  const int n0 = dton(d0), n1 = dton(d1);

  const float4* w40 = (const float4*)(W + (size_t)n0 * LATD);
  const float4* w41 = (const float4*)(W + (size_t)n1 * LATD);
  f32x2 acc0[NB] = {}, acc1[NB] = {};
#pragma unroll 4
  for (int k4 = 0; k4 < LATD / 4; ++k4) {
    float4 wa = w40[k4], wb = w41[k4];
    f32x2 wa01 = {wa.x, wa.y}, wa23 = {wa.z, wa.w};
    f32x2 wb01 = {wb.x, wb.y}, wb23 = {wb.z, wb.w};
#pragma unroll
    for (int b = 0; b < NB; ++b) {
      float4 lv = *(const float4*)&lds_lat[b * LATD + k4 * 4];  // broadcast
      f32x2 l01 = {lv.x, lv.y}, l23 = {lv.z, lv.w};
      acc0[b] = __builtin_elementwise_fma(wa01, l01, acc0[b]);
      acc0[b] = __builtin_elementwise_fma(wa23, l23, acc0[b]);
      acc1[b] = __builtin_elementwise_fma(wb01, l01, acc1[b]);
      acc1[b] = __builtin_elementwise_fma(wb23, l23, acc1[b]);
    }
  }

  float bv0 = bvec[n0], bv1 = bvec[n1];
#pragma unroll
  for (int b = 0; b < NB; ++b) {
    float ks0 = acc0[b].x + acc0[b].y + bv0;
    float ks1 = acc1[b].x + acc1[b].y + bv1;
    unsigned short h0 = f2bf(ks0), h1 = f2bf(ks1);
    Afh[(size_t)b * KSZ + d0] = h0;
    Afl[(size_t)b * KSZ + d0] = f2bf(ks0 - bf2f(h0));
    Afh[(size_t)b * KSZ + d1] = h1;
    Afl[(size_t)b * KSZ + d1] = f2bf(ks1 - bf2f(h1));
  }
}

// ---------------------------------------------------------------------------
// Kernel 2: prepass — x[b][fi][y][w] fp32  ->  padded channel-last bf16 hi/lo
// xT[b][y+1][x+1][fi], borders zero.  LDS tile transpose per (b, y-row).
// ---------------------------------------------------------------------------
__global__ __launch_bounds__(256) void prepass(
    const float* __restrict__ x, unsigned short* __restrict__ xTh,
    unsigned short* __restrict__ xTl) {
  __shared__ float tile[FIN_C * 65];     // pitch 65 to break bank conflicts
  const int y = blockIdx.x;              // 0..65 padded row
  const int b = blockIdx.y;
  const int tid = threadIdx.x;
  const bool interior = (y >= 1 && y <= HW);

  if (interior) {
    int yy = y - 1;
#pragma unroll
    for (int r = 0; r < 8; ++r) {
      int idx = tid + r * 256;           // 0..2047
      int fi = idx >> 4, q = idx & 15;
      float4 v = *(const float4*)(x + ((size_t)(b * FIN_C + fi) * (HW * HW)) +
                                  yy * HW + q * 4);
      float* dst = &tile[fi * 65 + q * 4];
      dst[0] = v.x; dst[1] = v.y; dst[2] = v.z; dst[3] = v.w;
    }
  }
  __syncthreads();

  for (int r = 0; r < 5; ++r) {
    int gg = tid + r * 256;              // granule: (x 0..65) x (fi8 0..15)
    if (gg >= XPAD * 16) break;
    int xc = gg >> 4, f8 = gg & 15;
    bf16x8 hv = {}, lv = {};
    if (interior && xc >= 1 && xc <= HW) {
#pragma unroll
      for (int e2 = 0; e2 < 8; ++e2) {
        float f = tile[(f8 * 8 + e2) * 65 + (xc - 1)];
        unsigned short h = f2bf(f);
        hv[e2] = (short)h;
        lv[e2] = (short)f2bf(f - bf2f(h));
      }
    }
    size_t off = ((size_t)b * XPAD * XPAD + (size_t)y * XPAD + xc) * FIN_C + f8 * 8;
    *(bf16x8*)(xTh + off) = hv;
    *(bf16x8*)(xTl + off) = lv;
  }
}

// ---------------------------------------------------------------------------
// Kernel 3: MFMA conv, double-buffered 2-phase schedule:
//   STAGE(s+1, other buf) -> ds_read+MFMA(s) -> vmcnt(0) -> barrier.
// The explicit vmcnt(0) BEFORE the barrier is the race fix (R3 post-mortem):
// all waves' DMA writes are complete before any wave crosses into s+1.
// LDS 64 KB = 2 x (Ah|Al|Bh|Bl).
// ---------------------------------------------------------------------------
__global__ __launch_bounds__(256, 2) void dyn_conv_mfma(
    const unsigned short* __restrict__ Afh, const unsigned short* __restrict__ Afl,
    const unsigned short* __restrict__ xTh, const unsigned short* __restrict__ xTl,
    const float* __restrict__ bias_ws, float* __restrict__ out) {
  __shared__ bf16x8 lds[4096];           // 64 KB: granules, buf1 at +2048
  char* ldsb = (char*)lds;
  const int pt = blockIdx.x;             // px tile (128 px = 2 image rows)
  const int b = blockIdx.y;
  const int tid = threadIdx.x;
  const int l = tid & 63;
  const int wid = tid >> 6;
  const int wr = wid >> 1, wc = wid & 1; // wave tile: 64 fo x 64 px

  f32x4 acc[4][4] = {};

  auto stage = [&](int s, int bufg) {    // bufg = granule base (0 or 2048)
    const int t = s >> 2, fib = s & 3;
    const int dy = t / 3 - 1, dx = t % 3 - 1;
    const size_t abase = (size_t)b * KSZ + (size_t)s * 4096;  // s == t*4+fib
    char* base0 = ldsb + (size_t)bufg * 16;
#pragma unroll
    for (int r = 0; r < 2; ++r) {
      int g = tid + r * 256;
      GLOAD16(Afh + abase + (size_t)g * 8, base0 + g * 16);
      GLOAD16(Afl + abase + (size_t)g * 8, base0 + 8192 + g * 16);
    }
#pragma unroll
    for (int r = 0; r < 2; ++r) {
      int g = tid + r * 256;
      int px = g >> 2;
      int fq = (g & 3) ^ (px & 3);       // inverse swizzle on source
      int yy = 2 * pt + (px >> 6) + dy + 1;
      int xx = (px & 63) + dx + 1;
      size_t boff = ((size_t)b * XPAD * XPAD + (size_t)yy * XPAD + xx) * FIN_C +
                    fib * 32 + fq * 8;
      GLOAD16(xTh + boff, base0 + 16384 + g * 16);
      GLOAD16(xTl + boff, base0 + 24576 + g * 16);
    }
  };

  stage(0, 0);
  VMCNT0_BARRIER();                      // buf0 fully landed for ALL waves

  for (int s = 0; s < 36; ++s) {
    const int cg = (s & 1) * 2048;       // current buffer granule base
    if (s < 35) stage(s + 1, 2048 - cg); // prefetch next into other buffer

    bf16x8 ah[4], al[4];
#pragma unroll
    for (int m = 0; m < 4; ++m) {
      ah[m] = lds[cg + (wr * 4 + m) * 64 + l];
      al[m] = lds[cg + 512 + (wr * 4 + m) * 64 + l];
    }
    const int kq = l >> 4;
#pragma unroll
    for (int nn = 0; nn < 4; ++nn) {
      int px = wc * 64 + nn * 16 + (l & 15);
      int slot = px * 4 + (kq ^ (px & 3));
      bf16x8 bh = lds[cg + 1024 + slot];
      bf16x8 bl = lds[cg + 1536 + slot];
#pragma unroll
      for (int m = 0; m < 4; ++m) {
        acc[m][nn] = __builtin_amdgcn_mfma_f32_16x16x32_bf16(ah[m], bh, acc[m][nn], 0, 0, 0);
        acc[m][nn] = __builtin_amdgcn_mfma_f32_16x16x32_bf16(ah[m], bl, acc[m][nn], 0, 0, 0);
        acc[m][nn] = __builtin_amdgcn_mfma_f32_16x16x32_bf16(al[m], bh, acc[m][nn], 0, 0, 0);
      }
    }
    VMCNT0_BARRIER();                    // drain next-tile DMA, then barrier
  }

  // ---- epilogue: D col = lane&15 (px), row = (lane>>4)*4 + reg (fo)
  float bvv[4][4];
#pragma unroll
  for (int m = 0; m < 4; ++m)
#pragma unroll
    for (int r = 0; r < 4; ++r)
      bvv[m][r] = bias_ws[b * FOUT_C + wr * 64 + m * 16 + (l >> 4) * 4 + r];

#pragma unroll
  for (int m = 0; m < 4; ++m) {
#pragma unroll
    for (int nn = 0; nn < 4; ++nn) {
#pragma unroll
      for (int r = 0; r < 4; ++r) {
        int fo = wr * 64 + m * 16 + (l >> 4) * 4 + r;
        int p = pt * 128 + wc * 64 + nn * 16 + (l & 15);
        out[((size_t)b * FOUT_C + fo) * (HW * HW) + p] = acc[m][nn][r] + bvv[m][r];
      }
    }
  }
}

// ===========================================================================
// Fallback (proven fp32 path) in case ws_size < WS_NEED
// ===========================================================================
__global__ __launch_bounds__(256) void hyper_gemm_fb(
    const float* __restrict__ lat, const float* __restrict__ W,
    const float* __restrict__ bvec, float* __restrict__ kt,
    float* __restrict__ bias_ws) {
  int d = blockIdx.x * 256 + threadIdx.x;
  if (d >= NROWS) return;
  long n; int fo; bool isBias = (d >= KSZ);
  if (!isBias) {
    fo = d & 127; int rest = d >> 7; int tap = rest % 9; int fi = rest / 9;
    n = (long)fo * (FIN_C * KK * KK) + fi * (KK * KK) + tap;
  } else { fo = d - KSZ; n = KSZ + fo; }
  const float* wrow = W + n * LATD;
  float bv = bvec[n];
  float acc[NB];
#pragma unroll
  for (int b = 0; b < NB; ++b) acc[b] = bv;
#pragma unroll 2
  for (int k = 0; k < LATD; k += 4) {
    float4 wv = *reinterpret_cast<const float4*>(wrow + k);
#pragma unroll
    for (int b = 0; b < NB; ++b) {
      acc[b] += wv.x * lat[b * LATD + k] + wv.y * lat[b * LATD + k + 1] +
                wv.z * lat[b * LATD + k + 2] + wv.w * lat[b * LATD + k + 3];
    }
  }
  if (!isBias) {
#pragma unroll
    for (int b = 0; b < NB; ++b) kt[(long)b * KSZ + d] = acc[b];
  } else {
#pragma unroll
    for (int b = 0; b < NB; ++b) bias_ws[b * FOUT_C + fo] = acc[b];
  }
}

__global__ __launch_bounds__(64) void dyn_conv_fb(
    const float* __restrict__ x, const float* __restrict__ kt,
    const float* __restrict__ bias_ws, float* __restrict__ out) {
  const int h = blockIdx.x, b = blockIdx.y, fo0 = blockIdx.z * 32;
  const int w = threadIdx.x;
  const float* xb = x + (long)b * FIN_C * (HW * HW);
  const float* ktb = kt + (long)b * KSZ;
  const float* bb = bias_ws + b * FOUT_C + fo0;
  float acc[32];
#pragma unroll
  for (int j = 0; j < 32; ++j) acc[j] = bb[j];
  for (int fi = 0; fi < FIN_C; ++fi) {
    float xv[9];
    const float* xr = xb + fi * (HW * HW);
#pragma unroll
    for (int ky = 0; ky < 3; ++ky) {
      int hy = h + ky - 1;
      bool vr = (hy >= 0) && (hy < HW);
      const float* row = xr + hy * HW;
      xv[ky * 3 + 0] = (vr && w > 0) ? row[w - 1] : 0.f;
      xv[ky * 3 + 1] = vr ? row[w] : 0.f;
      xv[ky * 3 + 2] = (vr && w < 63) ? row[w + 1] : 0.f;
    }
    const float* wt = ktb + fi * (KK * KK * FOUT_C) + fo0;
#pragma unroll
    for (int t = 0; t < 9; ++t)
#pragma unroll
      for (int j = 0; j < 32; ++j) acc[j] += xv[t] * wt[t * FOUT_C + j];
  }
  float* ob = out + (((long)b * FOUT_C + fo0) * HW + h) * HW + w;
#pragma unroll
  for (int j = 0; j < 32; ++j) ob[(long)j * (HW * HW)] = acc[j];
}

// ---------------------------------------------------------------------------
extern "C" void kernel_launch(void* const* d_in, const int* in_sizes, int n_in,
                              void* d_out, int out_size, void* d_ws, size_t ws_size,
                              hipStream_t stream) {
  const float* x   = (const float*)d_in[0];
  const float* lat = (const float*)d_in[1];
  const float* W   = (const float*)d_in[2];
  const float* bv  = (const float*)d_in[3];
  float* out = (float*)d_out;
  char* ws = (char*)d_ws;

  if (ws_size >= WS_NEED) {
    unsigned short* Afh = (unsigned short*)(ws + AFH_OFF);
    unsigned short* Afl = (unsigned short*)(ws + AFL_OFF);
    unsigned short* xTh = (unsigned short*)(ws + XTH_OFF);
    unsigned short* xTl = (unsigned short*)(ws + XTL_OFF);
    float* bias_ws = (float*)(ws + BIAS_OFF);

    hyper_gemm2<<<dim3(289), dim3(256), 0, stream>>>(lat, W, bv, Afh, Afl, bias_ws);
    prepass<<<dim3(XPAD, NB), dim3(256), 0, stream>>>(x, xTh, xTl);
    dyn_conv_mfma<<<dim3(32, NB), dim3(256), 0, stream>>>(Afh, Afl, xTh, xTl, bias_ws, out);
  } else {
    float* kt = (float*)d_ws;
    float* bias_ws = kt + (size_t)NB * KSZ;
    hyper_gemm_fb<<<dim3((NROWS + 255) / 256), dim3(256), 0, stream>>>(lat, W, bv, kt, bias_ws);
    dyn_conv_fb<<<dim3(HW, NB, 4), dim3(64), 0, stream>>>(x, kt, bias_ws, out);
  }
}

// Round 5
// 188.343 us; speedup vs baseline: 1.1816x; 1.1816x over previous
//
#include <hip/hip_runtime.h>

// Problem constants
#define NB     16
#define LATD   512
#define FIN_C  128
#define FOUT_C 128
#define KK     3
#define HW     64
#define KSZ    147456      // FOUT*FIN*K*K
#define NROWS  147584      // KSZ + FOUT (bias rows)

// padded channel-last x: [b][66][66][128]
#define XPAD   66
#define XT_BE  ((size_t)XPAD * XPAD * FIN_C)  // 557568 elems per b

// workspace layout (bytes)
#define AFH_OFF  ((size_t)0)
#define AF_BYTES ((size_t)NB * KSZ * 2)          // 4,718,592
#define AFL_OFF  (AFH_OFF + AF_BYTES)
#define XTH_OFF  (AFL_OFF + AF_BYTES)            // 9,437,184
#define XT_BYTES ((size_t)NB * XT_BE * 2)        // 17,842,176
#define XTL_OFF  (XTH_OFF + XT_BYTES)
#define BIAS_OFF (XTL_OFF + XT_BYTES)            // 45,121,536
#define WS_NEED  (BIAS_OFF + (size_t)NB * FOUT_C * 4)

typedef __attribute__((ext_vector_type(8))) short bf16x8;
typedef __attribute__((ext_vector_type(4))) float f32x4;
typedef __attribute__((ext_vector_type(2))) float f32x2;

#define GLOAD16(gp, lp)                                                        \
  __builtin_amdgcn_global_load_lds(                                            \
      (const __attribute__((address_space(1))) void*)(gp),                     \
      (__attribute__((address_space(3))) void*)(lp), 16, 0, 0)

// Explicit drain of this wave's outstanding global_load_lds BEFORE the
// barrier.  __syncthreads() alone is insufficient: the compiler may sink the
// per-wave vmcnt wait past s_barrier (legal by single-thread alias analysis,
// wrong cross-wave for DMA'd LDS granules consumed by OTHER waves).
#define VMCNT0_BARRIER()                                                       \
  do {                                                                         \
    asm volatile("s_waitcnt vmcnt(0)" ::: "memory");                           \
    __syncthreads();                                                           \
  } while (0)

__device__ __forceinline__ unsigned short f2bf(float f) {
  unsigned u = __builtin_bit_cast(unsigned, f);
  u += 0x7fffu + ((u >> 16) & 1u);       // RNE
  return (unsigned short)(u >> 16);
}
__device__ __forceinline__ float bf2f(unsigned short h) {
  return __builtin_bit_cast(float, ((unsigned)h) << 16);
}

// Af linear index d -> W row index n (A-fragment order for 16x16x32 MFMA)
__device__ __forceinline__ int dton(int d) {
  int e = d & 7, l = (d >> 3) & 63, mt = (d >> 9) & 7;
  int fib = (d >> 12) & 3, t = d >> 14;
  int fo = mt * 16 + (l & 15);
  int fi = fib * 32 + (l >> 4) * 8 + e;
  return fo * (FIN_C * KK * KK) + fi * (KK * KK) + t;
}

// ---------------------------------------------------------------------------
// Kernel 1: hyper GEMM, k-split teams.  512 threads = 2 teams x 256 cols.
// Team q streams W[row][q*256 .. q*256+255]; team 1 dumps f32x2 partials to
// LDS; team 0 combines + bf16 hi/lo split + store.  577 blocks x 8 waves
// -> ~16 waves/CU (the R4 regression was 289 blocks = 4.5 waves/CU, 853 GB/s).
// ---------------------------------------------------------------------------
__global__ __launch_bounds__(512, 4) void hyper_gemm3(
    const float* __restrict__ lat, const float* __restrict__ W,
    const float* __restrict__ bvec, unsigned short* __restrict__ Afh,
    unsigned short* __restrict__ Afl, float* __restrict__ bias_ws) {
  __shared__ float lds_lat[NB * LATD];   // 32 KB
  __shared__ f32x2 red[256][NB + 1];     // 34 KB, +1 pad breaks 128B stride
  const int tid = threadIdx.x;
#pragma unroll
  for (int r = 0; r < 4; ++r) {
    int i = tid + r * 512;
    *(float4*)&lds_lat[i * 4] = *(const float4*)(lat + i * 4);
  }
  __syncthreads();

  if (blockIdx.x == 576) {               // bias rows: one block, full K
    if (tid < FOUT_C) {
      int n = KSZ + tid;
      const float4* w4 = (const float4*)(W + (size_t)n * LATD);
      f32x2 acc[NB] = {};
#pragma unroll 8
      for (int k4 = 0; k4 < LATD / 4; ++k4) {
        float4 wv = w4[k4];
        f32x2 w01 = {wv.x, wv.y}, w23 = {wv.z, wv.w};
#pragma unroll
        for (int b = 0; b < NB; ++b) {
          float4 lv = *(const float4*)&lds_lat[b * LATD + k4 * 4];
          f32x2 l01 = {lv.x, lv.y}, l23 = {lv.z, lv.w};
          acc[b] = __builtin_elementwise_fma(w01, l01, acc[b]);
          acc[b] = __builtin_elementwise_fma(w23, l23, acc[b]);
        }
      }
      float bv = bvec[n];
#pragma unroll
      for (int b = 0; b < NB; ++b)
        bias_ws[b * FOUT_C + tid] = acc[b].x + acc[b].y + bv;
    }
    return;                              // whole block exits: no barrier below
  }

  const int col = tid & 255;
  const int team = tid >> 8;             // wave-uniform (waves 0-3 / 4-7)
  const int d = blockIdx.x * 256 + col;
  const int n = dton(d);

  const float4* w4 = (const float4*)(W + (size_t)n * LATD + team * 256);
  const float* latq = lds_lat + team * 256;
  f32x2 acc[NB] = {};
#pragma unroll 8
  for (int k4 = 0; k4 < 64; ++k4) {      // 64 x 16B = this team's half row
    float4 wv = w4[k4];
    f32x2 w01 = {wv.x, wv.y}, w23 = {wv.z, wv.w};
#pragma unroll
    for (int b = 0; b < NB; ++b) {
      float4 lv = *(const float4*)&latq[b * LATD + k4 * 4];  // broadcast
      f32x2 l01 = {lv.x, lv.y}, l23 = {lv.z, lv.w};
      acc[b] = __builtin_elementwise_fma(w01, l01, acc[b]);
      acc[b] = __builtin_elementwise_fma(w23, l23, acc[b]);
    }
  }

  if (team == 1) {
#pragma unroll
    for (int b = 0; b < NB; ++b) red[col][b] = acc[b];
  }
  __syncthreads();
  if (team == 0) {
    float bv = bvec[n];
#pragma unroll
    for (int b = 0; b < NB; ++b) {
      f32x2 o = red[col][b];
      float ks = (acc[b].x + o.x) + (acc[b].y + o.y) + bv;
      unsigned short h = f2bf(ks);
      Afh[(size_t)b * KSZ + d] = h;
      Afl[(size_t)b * KSZ + d] = f2bf(ks - bf2f(h));
    }
  }
}

// ---------------------------------------------------------------------------
// Kernel 2: prepass — x[b][fi][y][w] fp32  ->  padded channel-last bf16 hi/lo
// xT[b][y+1][x+1][fi], borders zero.  LDS tile transpose per (b, y-row).
// ---------------------------------------------------------------------------
__global__ __launch_bounds__(256) void prepass(
    const float* __restrict__ x, unsigned short* __restrict__ xTh,
    unsigned short* __restrict__ xTl) {
  __shared__ float tile[FIN_C * 65];     // pitch 65 to break bank conflicts
  const int y = blockIdx.x;              // 0..65 padded row
  const int b = blockIdx.y;
  const int tid = threadIdx.x;
  const bool interior = (y >= 1 && y <= HW);

  if (interior) {
    int yy = y - 1;
#pragma unroll
    for (int r = 0; r < 8; ++r) {
      int idx = tid + r * 256;           // 0..2047
      int fi = idx >> 4, q = idx & 15;
      float4 v = *(const float4*)(x + ((size_t)(b * FIN_C + fi) * (HW * HW)) +
                                  yy * HW + q * 4);
      float* dst = &tile[fi * 65 + q * 4];
      dst[0] = v.x; dst[1] = v.y; dst[2] = v.z; dst[3] = v.w;
    }
  }
  __syncthreads();

  for (int r = 0; r < 5; ++r) {
    int gg = tid + r * 256;              // granule: (x 0..65) x (fi8 0..15)
    if (gg >= XPAD * 16) break;
    int xc = gg >> 4, f8 = gg & 15;
    bf16x8 hv = {}, lv = {};
    if (interior && xc >= 1 && xc <= HW) {
#pragma unroll
      for (int e2 = 0; e2 < 8; ++e2) {
        float f = tile[(f8 * 8 + e2) * 65 + (xc - 1)];
        unsigned short h = f2bf(f);
        hv[e2] = (short)h;
        lv[e2] = (short)f2bf(f - bf2f(h));
      }
    }
    size_t off = ((size_t)b * XPAD * XPAD + (size_t)y * XPAD + xc) * FIN_C + f8 * 8;
    *(bf16x8*)(xTh + off) = hv;
    *(bf16x8*)(xTl + off) = lv;
  }
}

// ---------------------------------------------------------------------------
// Kernel 3: MFMA conv, double-buffered 2-phase schedule:
//   STAGE(s+1, other buf) -> ds_read+MFMA(s) -> vmcnt(0) -> barrier.
// The explicit vmcnt(0) BEFORE the barrier is the race fix (R3 post-mortem).
// LDS 64 KB = 2 x (Ah|Al|Bh|Bl).   ** Working well (~32 us) — unchanged. **
// ---------------------------------------------------------------------------
__global__ __launch_bounds__(256, 2) void dyn_conv_mfma(
    const unsigned short* __restrict__ Afh, const unsigned short* __restrict__ Afl,
    const unsigned short* __restrict__ xTh, const unsigned short* __restrict__ xTl,
    const float* __restrict__ bias_ws, float* __restrict__ out) {
  __shared__ bf16x8 lds[4096];           // 64 KB: granules, buf1 at +2048
  char* ldsb = (char*)lds;
  const int pt = blockIdx.x;             // px tile (128 px = 2 image rows)
  const int b = blockIdx.y;
  const int tid = threadIdx.x;
  const int l = tid & 63;
  const int wid = tid >> 6;
  const int wr = wid >> 1, wc = wid & 1; // wave tile: 64 fo x 64 px

  f32x4 acc[4][4] = {};

  auto stage = [&](int s, int bufg) {    // bufg = granule base (0 or 2048)
    const int t = s >> 2, fib = s & 3;
    const int dy = t / 3 - 1, dx = t % 3 - 1;
    const size_t abase = (size_t)b * KSZ + (size_t)s * 4096;  // s == t*4+fib
    char* base0 = ldsb + (size_t)bufg * 16;
#pragma unroll
    for (int r = 0; r < 2; ++r) {
      int g = tid + r * 256;
      GLOAD16(Afh + abase + (size_t)g * 8, base0 + g * 16);
      GLOAD16(Afl + abase + (size_t)g * 8, base0 + 8192 + g * 16);
    }
#pragma unroll
    for (int r = 0; r < 2; ++r) {
      int g = tid + r * 256;
      int px = g >> 2;
      int fq = (g & 3) ^ (px & 3);       // inverse swizzle on source
      int yy = 2 * pt + (px >> 6) + dy + 1;
      int xx = (px & 63) + dx + 1;
      size_t boff = ((size_t)b * XPAD * XPAD + (size_t)yy * XPAD + xx) * FIN_C +
                    fib * 32 + fq * 8;
      GLOAD16(xTh + boff, base0 + 16384 + g * 16);
      GLOAD16(xTl + boff, base0 + 24576 + g * 16);
    }
  };

  stage(0, 0);
  VMCNT0_BARRIER();                      // buf0 fully landed for ALL waves

  for (int s = 0; s < 36; ++s) {
    const int cg = (s & 1) * 2048;       // current buffer granule base
    if (s < 35) stage(s + 1, 2048 - cg); // prefetch next into other buffer

    bf16x8 ah[4], al[4];
#pragma unroll
    for (int m = 0; m < 4; ++m) {
      ah[m] = lds[cg + (wr * 4 + m) * 64 + l];
      al[m] = lds[cg + 512 + (wr * 4 + m) * 64 + l];
    }
    const int kq = l >> 4;
#pragma unroll
    for (int nn = 0; nn < 4; ++nn) {
      int px = wc * 64 + nn * 16 + (l & 15);
      int slot = px * 4 + (kq ^ (px & 3));
      bf16x8 bh = lds[cg + 1024 + slot];
      bf16x8 bl = lds[cg + 1536 + slot];
#pragma unroll
      for (int m = 0; m < 4; ++m) {
        acc[m][nn] = __builtin_amdgcn_mfma_f32_16x16x32_bf16(ah[m], bh, acc[m][nn], 0, 0, 0);
        acc[m][nn] = __builtin_amdgcn_mfma_f32_16x16x32_bf16(ah[m], bl, acc[m][nn], 0, 0, 0);
        acc[m][nn] = __builtin_amdgcn_mfma_f32_16x16x32_bf16(al[m], bh, acc[m][nn], 0, 0, 0);
      }
    }
    VMCNT0_BARRIER();                    // drain next-tile DMA, then barrier
  }

  // ---- epilogue: D col = lane&15 (px), row = (lane>>4)*4 + reg (fo)
  float bvv[4][4];
#pragma unroll
  for (int m = 0; m < 4; ++m)
#pragma unroll
    for (int r = 0; r < 4; ++r)
      bvv[m][r] = bias_ws[b * FOUT_C + wr * 64 + m * 16 + (l >> 4) * 4 + r];

#pragma unroll
  for (int m = 0; m < 4; ++m) {
#pragma unroll
    for (int nn = 0; nn < 4; ++nn) {
#pragma unroll
      for (int r = 0; r < 4; ++r) {
        int fo = wr * 64 + m * 16 + (l >> 4) * 4 + r;
        int p = pt * 128 + wc * 64 + nn * 16 + (l & 15);
        out[((size_t)b * FOUT_C + fo) * (HW * HW) + p] = acc[m][nn][r] + bvv[m][r];
      }
    }
  }
}

// ===========================================================================
// Fallback (proven fp32 path) in case ws_size < WS_NEED
// ===========================================================================
__global__ __launch_bounds__(256) void hyper_gemm_fb(
    const float* __restrict__ lat, const float* __restrict__ W,
    const float* __restrict__ bvec, float* __restrict__ kt,
    float* __restrict__ bias_ws) {
  int d = blockIdx.x * 256 + threadIdx.x;
  if (d >= NROWS) return;
  long n; int fo; bool isBias = (d >= KSZ);
  if (!isBias) {
    fo = d & 127; int rest = d >> 7; int tap = rest % 9; int fi = rest / 9;
    n = (long)fo * (FIN_C * KK * KK) + fi * (KK * KK) + tap;
  } else { fo = d - KSZ; n = KSZ + fo; }
  const float* wrow = W + n * LATD;
  float bv = bvec[n];
  float acc[NB];
#pragma unroll
  for (int b = 0; b < NB; ++b) acc[b] = bv;
#pragma unroll 2
  for (int k = 0; k < LATD; k += 4) {
    float4 wv = *reinterpret_cast<const float4*>(wrow + k);
#pragma unroll
    for (int b = 0; b < NB; ++b) {
      acc[b] += wv.x * lat[b * LATD + k] + wv.y * lat[b * LATD + k + 1] +
                wv.z * lat[b * LATD + k + 2] + wv.w * lat[b * LATD + k + 3];
    }
  }
  if (!isBias) {
#pragma unroll
    for (int b = 0; b < NB; ++b) kt[(long)b * KSZ + d] = acc[b];
  } else {
#pragma unroll
    for (int b = 0; b < NB; ++b) bias_ws[b * FOUT_C + fo] = acc[b];
  }
}

__global__ __launch_bounds__(64) void dyn_conv_fb(
    const float* __restrict__ x, const float* __restrict__ kt,
    const float* __restrict__ bias_ws, float* __restrict__ out) {
  const int h = blockIdx.x, b = blockIdx.y, fo0 = blockIdx.z * 32;
  const int w = threadIdx.x;
  const float* xb = x + (long)b * FIN_C * (HW * HW);
  const float* ktb = kt + (long)b * KSZ;
  const float* bb = bias_ws + b * FOUT_C + fo0;
  float acc[32];
#pragma unroll
  for (int j = 0; j < 32; ++j) acc[j] = bb[j];
  for (int fi = 0; fi < FIN_C; ++fi) {
    float xv[9];
    const float* xr = xb + fi * (HW * HW);
#pragma unroll
    for (int ky = 0; ky < 3; ++ky) {
      int hy = h + ky - 1;
      bool vr = (hy >= 0) && (hy < HW);
      const float* row = xr + hy * HW;
      xv[ky * 3 + 0] = (vr && w > 0) ? row[w - 1] : 0.f;
      xv[ky * 3 + 1] = vr ? row[w] : 0.f;
      xv[ky * 3 + 2] = (vr && w < 63) ? row[w + 1] : 0.f;
    }
    const float* wt = ktb + fi * (KK * KK * FOUT_C) + fo0;
#pragma unroll
    for (int t = 0; t < 9; ++t)
#pragma unroll
      for (int j = 0; j < 32; ++j) acc[j] += xv[t] * wt[t * FOUT_C + j];
  }
  float* ob = out + (((long)b * FOUT_C + fo0) * HW + h) * HW + w;
#pragma unroll
  for (int j = 0; j < 32; ++j) ob[(long)j * (HW * HW)] = acc[j];
}

// ---------------------------------------------------------------------------
extern "C" void kernel_launch(void* const* d_in, const int* in_sizes, int n_in,
                              void* d_out, int out_size, void* d_ws, size_t ws_size,
                              hipStream_t stream) {
  const float* x   = (const float*)d_in[0];
  const float* lat = (const float*)d_in[1];
  const float* W   = (const float*)d_in[2];
  const float* bv  = (const float*)d_in[3];
  float* out = (float*)d_out;
  char* ws = (char*)d_ws;

  if (ws_size >= WS_NEED) {
    unsigned short* Afh = (unsigned short*)(ws + AFH_OFF);
    unsigned short* Afl = (unsigned short*)(ws + AFL_OFF);
    unsigned short* xTh = (unsigned short*)(ws + XTH_OFF);
    unsigned short* xTl = (unsigned short*)(ws + XTL_OFF);
    float* bias_ws = (float*)(ws + BIAS_OFF);

    hyper_gemm3<<<dim3(577), dim3(512), 0, stream>>>(lat, W, bv, Afh, Afl, bias_ws);
    prepass<<<dim3(XPAD, NB), dim3(256), 0, stream>>>(x, xTh, xTl);
    dyn_conv_mfma<<<dim3(32, NB), dim3(256), 0, stream>>>(Afh, Afl, xTh, xTl, bias_ws, out);
  } else {
    float* kt = (float*)d_ws;
    float* bias_ws = kt + (size_t)NB * KSZ;
    hyper_gemm_fb<<<dim3((NROWS + 255) / 256), dim3(256), 0, stream>>>(lat, W, bv, kt, bias_ws);
    dyn_conv_fb<<<dim3(HW, NB, 4), dim3(64), 0, stream>>>(x, kt, bias_ws, out);
  }
}

// Round 7
// 168.765 us; speedup vs baseline: 1.3187x; 1.1160x over previous
//
#include <hip/hip_runtime.h>

// Problem constants
#define NB     16
#define LATD   512
#define FIN_C  128
#define FOUT_C 128
#define KK     3
#define HW     64
#define KSZ    147456      // FOUT*FIN*K*K
#define NROWS  147584      // KSZ + FOUT (bias rows)

// padded channel-last x: [b][66][66][128]
#define XPAD   66
#define XT_BE  ((size_t)XPAD * XPAD * FIN_C)  // 557568 elems per b

// workspace layout (bytes)
#define AFH_OFF  ((size_t)0)
#define AF_BYTES ((size_t)NB * KSZ * 2)          // 4,718,592
#define AFL_OFF  (AFH_OFF + AF_BYTES)
#define XTH_OFF  (AFL_OFF + AF_BYTES)            // 9,437,184
#define XT_BYTES ((size_t)NB * XT_BE * 2)        // 17,842,176
#define XTL_OFF  (XTH_OFF + XT_BYTES)
#define BIAS_OFF (XTL_OFF + XT_BYTES)            // 45,121,536
#define LATFH_OFF (BIAS_OFF + (size_t)NB * FOUT_C * 4)
#define LATF_BYTES ((size_t)NB * LATD * 2)       // 16,384
#define LATFL_OFF (LATFH_OFF + LATF_BYTES)
#define WS_NEED  (LATFL_OFF + LATF_BYTES)

typedef __attribute__((ext_vector_type(8))) short bf16x8;
typedef __attribute__((ext_vector_type(4))) float f32x4;
typedef __attribute__((ext_vector_type(2))) float f32x2;

#define GLOAD16(gp, lp)                                                        \
  __builtin_amdgcn_global_load_lds(                                            \
      (const __attribute__((address_space(1))) void*)(gp),                     \
      (__attribute__((address_space(3))) void*)(lp), 16, 0, 0)

// Explicit drain of this wave's outstanding global_load_lds BEFORE the
// barrier (R3 post-mortem race fix): __syncthreads() alone lets the compiler
// sink the per-wave vmcnt wait past s_barrier.
#define VMCNT0_BARRIER()                                                       \
  do {                                                                         \
    asm volatile("s_waitcnt vmcnt(0)" ::: "memory");                           \
    __syncthreads();                                                           \
  } while (0)

__device__ __forceinline__ unsigned short f2bf(float f) {
  unsigned u = __builtin_bit_cast(unsigned, f);
  u += 0x7fffu + ((u >> 16) & 1u);       // RNE
  return (unsigned short)(u >> 16);
}
__device__ __forceinline__ float bf2f(unsigned short h) {
  return __builtin_bit_cast(float, ((unsigned)h) << 16);
}

// 8-float -> bf16 hi/lo split (RNE both halves)
__device__ __forceinline__ void split8(float4 a, float4 b, bf16x8& h, bf16x8& lo) {
  float f[8] = {a.x, a.y, a.z, a.w, b.x, b.y, b.z, b.w};
#pragma unroll
  for (int e = 0; e < 8; ++e) {
    unsigned short hh = f2bf(f[e]);
    h[e] = (short)hh;
    lo[e] = (short)f2bf(f[e] - bf2f(hh));
  }
}

// Af linear index d -> W row index n (A-fragment order for 16x16x32 MFMA)
__device__ __forceinline__ int dton(int d) {
  int e = d & 7, l = (d >> 3) & 63, mt = (d >> 9) & 7;
  int fib = (d >> 12) & 3, t = d >> 14;
  int fo = mt * 16 + (l & 15);
  int fi = fib * 32 + (l >> 4) * 8 + e;
  return fo * (FIN_C * KK * KK) + fi * (KK * KK) + t;
}

// ---------------------------------------------------------------------------
// Kernel 0: latprep — lat fp32 -> bf16 hi/lo A-fragments in global (32 KB,
// L2-resident).  Granule g = it*64 + lane: lat[b=lane&15][it*32+(lane>>4)*8+e].
// ---------------------------------------------------------------------------
__global__ __launch_bounds__(256) void latprep(
    const float* __restrict__ lat, unsigned short* __restrict__ latFh,
    unsigned short* __restrict__ latFl) {
  const int t = threadIdx.x;
#pragma unroll
  for (int rr = 0; rr < 4; ++rr) {
    int g = t + rr * 256;              // 0..1023
    int it = g >> 6, lane = g & 63;
    int b = lane & 15;
    int k0 = it * 32 + (lane >> 4) * 8;
    float4 a = *(const float4*)(lat + b * LATD + k0);
    float4 bb = *(const float4*)(lat + b * LATD + k0 + 4);
    bf16x8 h, o;
    split8(a, bb, h, o);
    *(bf16x8*)(latFh + (size_t)g * 8) = h;
    *(bf16x8*)(latFl + (size_t)g * 8) = o;
  }
}

// ---------------------------------------------------------------------------
// Kernel 1: hyper GEMM via MFMA.  C[16 b][147456 n] = lat @ W^T + bvec,
// 3-product bf16 hi/lo split of BOTH operands, fp32 MFMA accumulate.
// The 16x reuse of W comes from the matrix unit — no LDS/scalar broadcast
// (R2-R5's bottleneck: 16 ds_read_b128 per 16B of W = 192 cyc/KB on the
// per-CU-shared LDS pipe vs a 104 cyc/KB HBM-pace budget).
// R6 post-mortem: the "+ bvec[n]" add was MISSING here (output absmax 3.57
// == conv(x, bvec) magnitude exactly).  Fixed: bv0/bv1 added per column.
// ---------------------------------------------------------------------------
__global__ __launch_bounds__(256, 4) void hyper_gemm_mfma(
    const float* __restrict__ lat, const float* __restrict__ W,
    const float* __restrict__ bvec, const unsigned short* __restrict__ latFh,
    const unsigned short* __restrict__ latFl, unsigned short* __restrict__ Afh,
    unsigned short* __restrict__ Afl, float* __restrict__ bias_ws) {
  const int bid = blockIdx.x, tid = threadIdx.x;

  if (bid == 1152) {                     // bias rows (straggler, hidden)
    if (tid >= FOUT_C) return;
    int n = KSZ + tid;
    const float4* w4 = (const float4*)(W + (size_t)n * LATD);
    f32x2 acc[NB] = {};
#pragma unroll 4
    for (int k4 = 0; k4 < LATD / 4; ++k4) {
      float4 wv = w4[k4];
      f32x2 w01 = {wv.x, wv.y}, w23 = {wv.z, wv.w};
#pragma unroll
      for (int b = 0; b < NB; ++b) {
        float4 lv = *(const float4*)(lat + b * LATD + k4 * 4);  // uniform
        f32x2 l01 = {lv.x, lv.y}, l23 = {lv.z, lv.w};
        acc[b] = __builtin_elementwise_fma(w01, l01, acc[b]);
        acc[b] = __builtin_elementwise_fma(w23, l23, acc[b]);
      }
    }
    float bv = bvec[n];
#pragma unroll
    for (int b = 0; b < NB; ++b)
      bias_ws[b * FOUT_C + tid] = acc[b].x + acc[b].y + bv;
    return;
  }

  const int l = tid & 63, wid = tid >> 6;
  const int dbase = bid * 128 + wid * 32;
  const int c = l & 15, kq = l >> 4;
  const int n0 = dton(dbase + c);
  const int n1 = dton(dbase + 16 + c);
  const float* wp0 = W + (size_t)n0 * LATD + kq * 8;
  const float* wp1 = W + (size_t)n1 * LATD + kq * 8;
  const bf16x8* lFh = (const bf16x8*)latFh + l;
  const bf16x8* lFl = (const bf16x8*)latFl + l;

  f32x4 acc0 = {}, acc1 = {};
#pragma unroll
  for (int it = 0; it < 16; ++it) {      // K = 16 x 32; offsets fold to imm
    bf16x8 lah = lFh[it * 64];           // lat A-frag hi (L2 broadcast)
    bf16x8 lal = lFl[it * 64];           // lat A-frag lo
    float4 a0 = *(const float4*)(wp0 + it * 32);
    float4 b0 = *(const float4*)(wp0 + it * 32 + 4);
    float4 a1 = *(const float4*)(wp1 + it * 32);
    float4 b1 = *(const float4*)(wp1 + it * 32 + 4);
    bf16x8 h0, o0, h1, o1;
    split8(a0, b0, h0, o0);
    split8(a1, b1, h1, o1);
    acc0 = __builtin_amdgcn_mfma_f32_16x16x32_bf16(lah, h0, acc0, 0, 0, 0);
    acc0 = __builtin_amdgcn_mfma_f32_16x16x32_bf16(lal, h0, acc0, 0, 0, 0);
    acc0 = __builtin_amdgcn_mfma_f32_16x16x32_bf16(lah, o0, acc0, 0, 0, 0);
    acc1 = __builtin_amdgcn_mfma_f32_16x16x32_bf16(lah, h1, acc1, 0, 0, 0);
    acc1 = __builtin_amdgcn_mfma_f32_16x16x32_bf16(lal, h1, acc1, 0, 0, 0);
    acc1 = __builtin_amdgcn_mfma_f32_16x16x32_bf16(lah, o1, acc1, 0, 0, 0);
  }

  // epilogue: C row = b = kq*4+r, col = n-offset = c.  ks(+bvec) -> bf16 hi/lo.
  const float bv0 = bvec[n0];            // R6 fix: hypernet bias per column
  const float bv1 = bvec[n1];
#pragma unroll
  for (int r = 0; r < 4; ++r) {
    int b = kq * 4 + r;
    size_t base = (size_t)b * KSZ + dbase;
    float ks0 = acc0[r] + bv0, ks1 = acc1[r] + bv1;
    unsigned short h0 = f2bf(ks0), h1 = f2bf(ks1);
    Afh[base + c] = h0;
    Afl[base + c] = f2bf(ks0 - bf2f(h0));
    Afh[base + 16 + c] = h1;
    Afl[base + 16 + c] = f2bf(ks1 - bf2f(h1));
  }
}

// ---------------------------------------------------------------------------
// Kernel 2: prepass — x[b][fi][y][w] fp32  ->  padded channel-last bf16 hi/lo
// xT[b][y+1][x+1][fi], borders zero.  LDS tile transpose per (b, y-row).
// ---------------------------------------------------------------------------
__global__ __launch_bounds__(256) void prepass(
    const float* __restrict__ x, unsigned short* __restrict__ xTh,
    unsigned short* __restrict__ xTl) {
  __shared__ float tile[FIN_C * 65];     // pitch 65 to break bank conflicts
  const int y = blockIdx.x;              // 0..65 padded row
  const int b = blockIdx.y;
  const int tid = threadIdx.x;
  const bool interior = (y >= 1 && y <= HW);

  if (interior) {
    int yy = y - 1;
#pragma unroll
    for (int r = 0; r < 8; ++r) {
      int idx = tid + r * 256;           // 0..2047
      int fi = idx >> 4, q = idx & 15;
      float4 v = *(const float4*)(x + ((size_t)(b * FIN_C + fi) * (HW * HW)) +
                                  yy * HW + q * 4);
      float* dst = &tile[fi * 65 + q * 4];
      dst[0] = v.x; dst[1] = v.y; dst[2] = v.z; dst[3] = v.w;
    }
  }
  __syncthreads();

  for (int r = 0; r < 5; ++r) {
    int gg = tid + r * 256;              // granule: (x 0..65) x (fi8 0..15)
    if (gg >= XPAD * 16) break;
    int xc = gg >> 4, f8 = gg & 15;
    bf16x8 hv = {}, lv = {};
    if (interior && xc >= 1 && xc <= HW) {
#pragma unroll
      for (int e2 = 0; e2 < 8; ++e2) {
        float f = tile[(f8 * 8 + e2) * 65 + (xc - 1)];
        unsigned short h = f2bf(f);
        hv[e2] = (short)h;
        lv[e2] = (short)f2bf(f - bf2f(h));
      }
    }
    size_t off = ((size_t)b * XPAD * XPAD + (size_t)y * XPAD + xc) * FIN_C + f8 * 8;
    *(bf16x8*)(xTh + off) = hv;
    *(bf16x8*)(xTl + off) = lv;
  }
}

// ---------------------------------------------------------------------------
// Kernel 3: MFMA conv, double-buffered 2-phase schedule (unchanged, ~32 us):
//   STAGE(s+1, other buf) -> ds_read+MFMA(s) -> vmcnt(0) -> barrier.
// ---------------------------------------------------------------------------
__global__ __launch_bounds__(256, 2) void dyn_conv_mfma(
    const unsigned short* __restrict__ Afh, const unsigned short* __restrict__ Afl,
    const unsigned short* __restrict__ xTh, const unsigned short* __restrict__ xTl,
    const float* __restrict__ bias_ws, float* __restrict__ out) {
  __shared__ bf16x8 lds[4096];           // 64 KB: granules, buf1 at +2048
  char* ldsb = (char*)lds;
  const int pt = blockIdx.x;             // px tile (128 px = 2 image rows)
  const int b = blockIdx.y;
  const int tid = threadIdx.x;
  const int l = tid & 63;
  const int wid = tid >> 6;
  const int wr = wid >> 1, wc = wid & 1; // wave tile: 64 fo x 64 px

  f32x4 acc[4][4] = {};

  auto stage = [&](int s, int bufg) {    // bufg = granule base (0 or 2048)
    const int t = s >> 2, fib = s & 3;
    const int dy = t / 3 - 1, dx = t % 3 - 1;
    const size_t abase = (size_t)b * KSZ + (size_t)s * 4096;  // s == t*4+fib
    char* base0 = ldsb + (size_t)bufg * 16;
#pragma unroll
    for (int r = 0; r < 2; ++r) {
      int g = tid + r * 256;
      GLOAD16(Afh + abase + (size_t)g * 8, base0 + g * 16);
      GLOAD16(Afl + abase + (size_t)g * 8, base0 + 8192 + g * 16);
    }
#pragma unroll
    for (int r = 0; r < 2; ++r) {
      int g = tid + r * 256;
      int px = g >> 2;
      int fq = (g & 3) ^ (px & 3);       // inverse swizzle on source
      int yy = 2 * pt + (px >> 6) + dy + 1;
      int xx = (px & 63) + dx + 1;
      size_t boff = ((size_t)b * XPAD * XPAD + (size_t)yy * XPAD + xx) * FIN_C +
                    fib * 32 + fq * 8;
      GLOAD16(xTh + boff, base0 + 16384 + g * 16);
      GLOAD16(xTl + boff, base0 + 24576 + g * 16);
    }
  };

  stage(0, 0);
  VMCNT0_BARRIER();                      // buf0 fully landed for ALL waves

  for (int s = 0; s < 36; ++s) {
    const int cg = (s & 1) * 2048;       // current buffer granule base
    if (s < 35) stage(s + 1, 2048 - cg); // prefetch next into other buffer

    bf16x8 ah[4], al[4];
#pragma unroll
    for (int m = 0; m < 4; ++m) {
      ah[m] = lds[cg + (wr * 4 + m) * 64 + l];
      al[m] = lds[cg + 512 + (wr * 4 + m) * 64 + l];
    }
    const int kq = l >> 4;
#pragma unroll
    for (int nn = 0; nn < 4; ++nn) {
      int px = wc * 64 + nn * 16 + (l & 15);
      int slot = px * 4 + (kq ^ (px & 3));
      bf16x8 bh = lds[cg + 1024 + slot];
      bf16x8 bl = lds[cg + 1536 + slot];
#pragma unroll
      for (int m = 0; m < 4; ++m) {
        acc[m][nn] = __builtin_amdgcn_mfma_f32_16x16x32_bf16(ah[m], bh, acc[m][nn], 0, 0, 0);
        acc[m][nn] = __builtin_amdgcn_mfma_f32_16x16x32_bf16(ah[m], bl, acc[m][nn], 0, 0, 0);
        acc[m][nn] = __builtin_amdgcn_mfma_f32_16x16x32_bf16(al[m], bh, acc[m][nn], 0, 0, 0);
      }
    }
    VMCNT0_BARRIER();                    // drain next-tile DMA, then barrier
  }

  // ---- epilogue: D col = lane&15 (px), row = (lane>>4)*4 + reg (fo)
  float bvv[4][4];
#pragma unroll
  for (int m = 0; m < 4; ++m)
#pragma unroll
    for (int r = 0; r < 4; ++r)
      bvv[m][r] = bias_ws[b * FOUT_C + wr * 64 + m * 16 + (l >> 4) * 4 + r];

#pragma unroll
  for (int m = 0; m < 4; ++m) {
#pragma unroll
    for (int nn = 0; nn < 4; ++nn) {
#pragma unroll
      for (int r = 0; r < 4; ++r) {
        int fo = wr * 64 + m * 16 + (l >> 4) * 4 + r;
        int p = pt * 128 + wc * 64 + nn * 16 + (l & 15);
        out[((size_t)b * FOUT_C + fo) * (HW * HW) + p] = acc[m][nn][r] + bvv[m][r];
      }
    }
  }
}

// ===========================================================================
// Fallback (proven fp32 path) in case ws_size < WS_NEED
// ===========================================================================
__global__ __launch_bounds__(256) void hyper_gemm_fb(
    const float* __restrict__ lat, const float* __restrict__ W,
    const float* __restrict__ bvec, float* __restrict__ kt,
    float* __restrict__ bias_ws) {
  int d = blockIdx.x * 256 + threadIdx.x;
  if (d >= NROWS) return;
  long n; int fo; bool isBias = (d >= KSZ);
  if (!isBias) {
    fo = d & 127; int rest = d >> 7; int tap = rest % 9; int fi = rest / 9;
    n = (long)fo * (FIN_C * KK * KK) + fi * (KK * KK) + tap;
  } else { fo = d - KSZ; n = KSZ + fo; }
  const float* wrow = W + n * LATD;
  float bv = bvec[n];
  float acc[NB];
#pragma unroll
  for (int b = 0; b < NB; ++b) acc[b] = bv;
#pragma unroll 2
  for (int k = 0; k < LATD; k += 4) {
    float4 wv = *reinterpret_cast<const float4*>(wrow + k);
#pragma unroll
    for (int b = 0; b < NB; ++b) {
      acc[b] += wv.x * lat[b * LATD + k] + wv.y * lat[b * LATD + k + 1] +
                wv.z * lat[b * LATD + k + 2] + wv.w * lat[b * LATD + k + 3];
    }
  }
  if (!isBias) {
#pragma unroll
    for (int b = 0; b < NB; ++b) kt[(long)b * KSZ + d] = acc[b];
  } else {
#pragma unroll
    for (int b = 0; b < NB; ++b) bias_ws[b * FOUT_C + fo] = acc[b];
  }
}

__global__ __launch_bounds__(64) void dyn_conv_fb(
    const float* __restrict__ x, const float* __restrict__ kt,
    const float* __restrict__ bias_ws, float* __restrict__ out) {
  const int h = blockIdx.x, b = blockIdx.y, fo0 = blockIdx.z * 32;
  const int w = threadIdx.x;
  const float* xb = x + (long)b * FIN_C * (HW * HW);
  const float* ktb = kt + (long)b * KSZ;
  const float* bb = bias_ws + b * FOUT_C + fo0;
  float acc[32];
#pragma unroll
  for (int j = 0; j < 32; ++j) acc[j] = bb[j];
  for (int fi = 0; fi < FIN_C; ++fi) {
    float xv[9];
    const float* xr = xb + fi * (HW * HW);
#pragma unroll
    for (int ky = 0; ky < 3; ++ky) {
      int hy = h + ky - 1;
      bool vr = (hy >= 0) && (hy < HW);
      const float* row = xr + hy * HW;
      xv[ky * 3 + 0] = (vr && w > 0) ? row[w - 1] : 0.f;
      xv[ky * 3 + 1] = vr ? row[w] : 0.f;
      xv[ky * 3 + 2] = (vr && w < 63) ? row[w + 1] : 0.f;
    }
    const float* wt = ktb + fi * (KK * KK * FOUT_C) + fo0;
#pragma unroll
    for (int t = 0; t < 9; ++t)
#pragma unroll
      for (int j = 0; j < 32; ++j) acc[j] += xv[t] * wt[t * FOUT_C + j];
  }
  float* ob = out + (((long)b * FOUT_C + fo0) * HW + h) * HW + w;
#pragma unroll
  for (int j = 0; j < 32; ++j) ob[(long)j * (HW * HW)] = acc[j];
}

// ---------------------------------------------------------------------------
extern "C" void kernel_launch(void* const* d_in, const int* in_sizes, int n_in,
                              void* d_out, int out_size, void* d_ws, size_t ws_size,
                              hipStream_t stream) {
  const float* x   = (const float*)d_in[0];
  const float* lat = (const float*)d_in[1];
  const float* W   = (const float*)d_in[2];
  const float* bv  = (const float*)d_in[3];
  float* out = (float*)d_out;
  char* ws = (char*)d_ws;

  if (ws_size >= WS_NEED) {
    unsigned short* Afh = (unsigned short*)(ws + AFH_OFF);
    unsigned short* Afl = (unsigned short*)(ws + AFL_OFF);
    unsigned short* xTh = (unsigned short*)(ws + XTH_OFF);
    unsigned short* xTl = (unsigned short*)(ws + XTL_OFF);
    float* bias_ws = (float*)(ws + BIAS_OFF);
    unsigned short* latFh = (unsigned short*)(ws + LATFH_OFF);
    unsigned short* latFl = (unsigned short*)(ws + LATFL_OFF);

    latprep<<<dim3(1), dim3(256), 0, stream>>>(lat, latFh, latFl);
    hyper_gemm_mfma<<<dim3(1153), dim3(256), 0, stream>>>(
        lat, W, bv, latFh, latFl, Afh, Afl, bias_ws);
    prepass<<<dim3(XPAD, NB), dim3(256), 0, stream>>>(x, xTh, xTl);
    dyn_conv_mfma<<<dim3(32, NB), dim3(256), 0, stream>>>(Afh, Afl, xTh, xTl, bias_ws, out);
  } else {
    float* kt = (float*)d_ws;
    float* bias_ws = kt + (size_t)NB * KSZ;
    hyper_gemm_fb<<<dim3((NROWS + 255) / 256), dim3(256), 0, stream>>>(lat, W, bv, kt, bias_ws);
    dyn_conv_fb<<<dim3(HW, NB, 4), dim3(64), 0, stream>>>(x, kt, bias_ws, out);
  }
}

// Round 10
// 141.728 us; speedup vs baseline: 1.5703x; 1.1908x over previous
//
#include <hip/hip_runtime.h>

// Problem constants
#define NB     16
#define LATD   512
#define FIN_C  128
#define FOUT_C 128
#define KK     3
#define HW     64
#define KSZ    147456      // FOUT*FIN*K*K
#define NROWS  147584      // KSZ + FOUT (bias rows)

// padded channel-last x: [b][66][66][128]
#define XPAD   66
#define XT_BE  ((size_t)XPAD * XPAD * FIN_C)  // 557568 elems per b

// workspace layout (bytes) — single-bf16 scheme (no lo arrays)
#define AFH_OFF  ((size_t)0)
#define AF_BYTES ((size_t)NB * KSZ * 2)          // 4,718,592
#define XTH_OFF  (AFH_OFF + AF_BYTES)
#define XT_BYTES ((size_t)NB * XT_BE * 2)        // 17,842,176
#define KST_OFF  (XTH_OFF + XT_BYTES)            // ks_tmp[n][16] fp32
#define KST_BYTES ((size_t)KSZ * NB * 4)         // 9,437,184
#define BIAS_OFF (KST_OFF + KST_BYTES)
#define LATFH_OFF (BIAS_OFF + (size_t)NB * FOUT_C * 4)
#define LATF_BYTES ((size_t)NB * LATD * 2)       // 16,384
#define WS_NEED  (LATFH_OFF + LATF_BYTES)

typedef __attribute__((ext_vector_type(8))) short bf16x8;
typedef __attribute__((ext_vector_type(4))) float f32x4;
typedef __attribute__((ext_vector_type(2))) float f32x2;

#define GLOAD16(gp, lp)                                                        \
  __builtin_amdgcn_global_load_lds(                                            \
      (const __attribute__((address_space(1))) void*)(gp),                     \
      (__attribute__((address_space(3))) void*)(lp), 16, 0, 0)

// Explicit drain of this wave's outstanding global_load_lds BEFORE the
// barrier (R3 post-mortem race fix): __syncthreads() alone lets the compiler
// sink the per-wave vmcnt wait past s_barrier.
#define VMCNT0_BARRIER()                                                       \
  do {                                                                         \
    asm volatile("s_waitcnt vmcnt(0)" ::: "memory");                           \
    __syncthreads();                                                           \
  } while (0)

__device__ __forceinline__ unsigned short f2bf(float f) {
  unsigned u = __builtin_bit_cast(unsigned, f);
  u += 0x7fffu + ((u >> 16) & 1u);       // RNE
  return (unsigned short)(u >> 16);
}

// 8 floats -> bf16x8 (RNE)
__device__ __forceinline__ bf16x8 cvt8(float4 a, float4 b) {
  bf16x8 h;
  h[0] = (short)f2bf(a.x); h[1] = (short)f2bf(a.y);
  h[2] = (short)f2bf(a.z); h[3] = (short)f2bf(a.w);
  h[4] = (short)f2bf(b.x); h[5] = (short)f2bf(b.y);
  h[6] = (short)f2bf(b.z); h[7] = (short)f2bf(b.w);
  return h;
}

// Af linear index d -> W row index n (A-fragment order for 16x16x32 MFMA)
__device__ __forceinline__ int dton(int d) {
  int e = d & 7, l = (d >> 3) & 63, mt = (d >> 9) & 7;
  int fib = (d >> 12) & 3, t = d >> 14;
  int fo = mt * 16 + (l & 15);
  int fi = fib * 32 + (l >> 4) * 8 + e;
  return fo * (FIN_C * KK * KK) + fi * (KK * KK) + t;
}

// ---------------------------------------------------------------------------
// Kernel 0: latprep — lat fp32 -> bf16 A-fragments in global (16 KB,
// L2-resident).  Granule g = it*64 + lane: lat[b=lane&15][it*32+(lane>>4)*8+e].
// ---------------------------------------------------------------------------
__global__ __launch_bounds__(256) void latprep(
    const float* __restrict__ lat, unsigned short* __restrict__ latFh) {
  const int t = threadIdx.x;
#pragma unroll
  for (int rr = 0; rr < 4; ++rr) {
    int g = t + rr * 256;              // 0..1023
    int it = g >> 6, lane = g & 63;
    int b = lane & 15;
    int k0 = it * 32 + (lane >> 4) * 8;
    float4 a = *(const float4*)(lat + b * LATD + k0);
    float4 bb = *(const float4*)(lat + b * LATD + k0 + 4);
    *(bf16x8*)(latFh + (size_t)g * 8) = cvt8(a, bb);
  }
}

// ---------------------------------------------------------------------------
// Kernel 1: hyper GEMM via MFMA, W read CONTIGUOUSLY.
// R7 post-mortem: d-major mapping scattered W rows at 18KB stride ->
// ~131K interleaved 128B streams -> ~2.5 TB/s effective HBM.  A wave owns
// 32 CONSECUTIVE W rows (dense 64KB panel); the d-permutation moves to the
// 9.4MB ks_tmp side (reshuffle kernel).
// R8 post-mortem (coverage bug): blocks strided 256 rows but 4 waves x 32
// = 128 rows of coverage -> half of ks_tmp never written (absmax 57.6 ==
// half-garbage-weights magnitude).  Fix: R7's proven grid shape — 1152
// work blocks, n0 = bid*128 + wid*32 (1152*128 = 147456 exact).
// Output: ks_tmp[n][b] fp32 (+bvec), bias rows -> bias_ws.
// ---------------------------------------------------------------------------
__global__ __launch_bounds__(256, 4) void hyper_gemm_mfma2(
    const float* __restrict__ lat, const float* __restrict__ W,
    const float* __restrict__ bvec, const unsigned short* __restrict__ latFh,
    float* __restrict__ ks_tmp, float* __restrict__ bias_ws) {
  const int bid = blockIdx.x, tid = threadIdx.x;

  if (bid == 1152) {                     // bias rows (straggler, hidden)
    if (tid >= FOUT_C) return;
    int n = KSZ + tid;
    const float4* w4 = (const float4*)(W + (size_t)n * LATD);
    f32x2 acc[NB] = {};
#pragma unroll 4
    for (int k4 = 0; k4 < LATD / 4; ++k4) {
      float4 wv = w4[k4];
      f32x2 w01 = {wv.x, wv.y}, w23 = {wv.z, wv.w};
#pragma unroll
      for (int b = 0; b < NB; ++b) {
        float4 lv = *(const float4*)(lat + b * LATD + k4 * 4);  // uniform
        f32x2 l01 = {lv.x, lv.y}, l23 = {lv.z, lv.w};
        acc[b] = __builtin_elementwise_fma(w01, l01, acc[b]);
        acc[b] = __builtin_elementwise_fma(w23, l23, acc[b]);
      }
    }
    float bv = bvec[n];
#pragma unroll
    for (int b = 0; b < NB; ++b)
      bias_ws[b * FOUT_C + tid] = acc[b].x + acc[b].y + bv;
    return;
  }

  const int l = tid & 63, wid = tid >> 6;
  const int n0 = bid * 128 + wid * 32;   // 32 consecutive W rows per wave
  const int c = l & 15, kq = l >> 4;
  const float* wp0 = W + (size_t)(n0 + c) * LATD + kq * 8;
  const float* wp1 = W + (size_t)(n0 + 16 + c) * LATD + kq * 8;
  const bf16x8* lFh = (const bf16x8*)latFh + l;

  f32x4 acc0 = {}, acc1 = {};
#pragma unroll
  for (int it = 0; it < 16; ++it) {      // K = 16 x 32; offsets fold to imm
    bf16x8 lah = lFh[it * 64];           // lat A-frag (L2 broadcast)
    float4 a0 = *(const float4*)(wp0 + it * 32);
    float4 b0 = *(const float4*)(wp0 + it * 32 + 4);
    float4 a1 = *(const float4*)(wp1 + it * 32);
    float4 b1 = *(const float4*)(wp1 + it * 32 + 4);
    bf16x8 h0 = cvt8(a0, b0), h1 = cvt8(a1, b1);
    acc0 = __builtin_amdgcn_mfma_f32_16x16x32_bf16(lah, h0, acc0, 0, 0, 0);
    acc1 = __builtin_amdgcn_mfma_f32_16x16x32_bf16(lah, h1, acc1, 0, 0, 0);
  }

  // epilogue: C row = b = kq*4+r, col = c.  ks_tmp[n][b] = acc + bvec[n].
  const float bv0 = bvec[n0 + c];
  const float bv1 = bvec[n0 + 16 + c];
#pragma unroll
  for (int r = 0; r < 4; ++r) {
    int b = kq * 4 + r;
    ks_tmp[(size_t)(n0 + c) * NB + b] = acc0[r] + bv0;
    ks_tmp[(size_t)(n0 + 16 + c) * NB + b] = acc1[r] + bv1;
  }
}

// ---------------------------------------------------------------------------
// Kernel 1b: reshuffle — ks_tmp[n][16b] fp32 -> Afh[b][d] bf16 (d-major,
// A-fragment order).  Gather 64B/thread (scatter borne by 9.4MB, not 302MB);
// stores fully coalesced per b.
// ---------------------------------------------------------------------------
__global__ __launch_bounds__(256) void reshuffle(
    const float* __restrict__ ks_tmp, unsigned short* __restrict__ Afh) {
  const int d = blockIdx.x * 256 + threadIdx.x;   // 576 blocks cover KSZ
  const int n = dton(d);
  const float4* p = (const float4*)(ks_tmp + (size_t)n * NB);
  float4 v0 = p[0], v1 = p[1], v2 = p[2], v3 = p[3];
  float v[16] = {v0.x, v0.y, v0.z, v0.w, v1.x, v1.y, v1.z, v1.w,
                 v2.x, v2.y, v2.z, v2.w, v3.x, v3.y, v3.z, v3.w};
#pragma unroll
  for (int b = 0; b < NB; ++b)
    Afh[(size_t)b * KSZ + d] = f2bf(v[b]);
}

// ---------------------------------------------------------------------------
// Kernel 2: prepass — x fp32 -> padded channel-last bf16 xT[b][y+1][x+1][fi].
// ---------------------------------------------------------------------------
__global__ __launch_bounds__(256) void prepass(
    const float* __restrict__ x, unsigned short* __restrict__ xTh) {
  __shared__ float tile[FIN_C * 65];     // pitch 65 to break bank conflicts
  const int y = blockIdx.x;              // 0..65 padded row
  const int b = blockIdx.y;
  const int tid = threadIdx.x;
  const bool interior = (y >= 1 && y <= HW);

  if (interior) {
    int yy = y - 1;
#pragma unroll
    for (int r = 0; r < 8; ++r) {
      int idx = tid + r * 256;           // 0..2047
      int fi = idx >> 4, q = idx & 15;
      float4 v = *(const float4*)(x + ((size_t)(b * FIN_C + fi) * (HW * HW)) +
                                  yy * HW + q * 4);
      float* dst = &tile[fi * 65 + q * 4];
      dst[0] = v.x; dst[1] = v.y; dst[2] = v.z; dst[3] = v.w;
    }
  }
  __syncthreads();

  for (int r = 0; r < 5; ++r) {
    int gg = tid + r * 256;              // granule: (x 0..65) x (fi8 0..15)
    if (gg >= XPAD * 16) break;
    int xc = gg >> 4, f8 = gg & 15;
    bf16x8 hv = {};
    if (interior && xc >= 1 && xc <= HW) {
#pragma unroll
      for (int e2 = 0; e2 < 8; ++e2) {
        float f = tile[(f8 * 8 + e2) * 65 + (xc - 1)];
        hv[e2] = (short)f2bf(f);
      }
    }
    size_t off = ((size_t)b * XPAD * XPAD + (size_t)y * XPAD + xc) * FIN_C + f8 * 8;
    *(bf16x8*)(xTh + off) = hv;
  }
}

// ---------------------------------------------------------------------------
// Kernel 3: MFMA conv, single bf16 product (error budget ~0.35 absmax vs
// 1.93 threshold), double-buffered 2-phase schedule:
//   STAGE(s+1, other buf) -> ds_read+MFMA(s) -> vmcnt(0) -> barrier.
// LDS 32 KB = 2 x (Ah | Bh); 3 blocks/CU.
// ---------------------------------------------------------------------------
__global__ __launch_bounds__(256, 3) void dyn_conv_mfma(
    const unsigned short* __restrict__ Afh, const unsigned short* __restrict__ xTh,
    const float* __restrict__ bias_ws, float* __restrict__ out) {
  __shared__ bf16x8 lds[2048];           // 32 KB: granules, buf1 at +1024
  char* ldsb = (char*)lds;
  const int pt = blockIdx.x;             // px tile (128 px = 2 image rows)
  const int b = blockIdx.y;
  const int tid = threadIdx.x;
  const int l = tid & 63;
  const int wid = tid >> 6;
  const int wr = wid >> 1, wc = wid & 1; // wave tile: 64 fo x 64 px

  f32x4 acc[4][4] = {};

  auto stage = [&](int s, int bufg) {    // bufg = granule base (0 or 1024)
    const int t = s >> 2, fib = s & 3;
    const int dy = t / 3 - 1, dx = t % 3 - 1;
    const size_t abase = (size_t)b * KSZ + (size_t)s * 4096;  // s == t*4+fib
    char* base0 = ldsb + (size_t)bufg * 16;
#pragma unroll
    for (int r = 0; r < 2; ++r) {
      int g = tid + r * 256;
      GLOAD16(Afh + abase + (size_t)g * 8, base0 + g * 16);
    }
#pragma unroll
    for (int r = 0; r < 2; ++r) {
      int g = tid + r * 256;
      int px = g >> 2;
      int fq = (g & 3) ^ (px & 3);       // inverse swizzle on source
      int yy = 2 * pt + (px >> 6) + dy + 1;
      int xx = (px & 63) + dx + 1;
      size_t boff = ((size_t)b * XPAD * XPAD + (size_t)yy * XPAD + xx) * FIN_C +
                    fib * 32 + fq * 8;
      GLOAD16(xTh + boff, base0 + 8192 + g * 16);
    }
  };

  stage(0, 0);
  VMCNT0_BARRIER();                      // buf0 fully landed for ALL waves

  for (int s = 0; s < 36; ++s) {
    const int cg = (s & 1) * 1024;       // current buffer granule base
    if (s < 35) stage(s + 1, 1024 - cg); // prefetch next into other buffer

    bf16x8 ah[4];
#pragma unroll
    for (int m = 0; m < 4; ++m)
      ah[m] = lds[cg + (wr * 4 + m) * 64 + l];
    const int kq = l >> 4;
#pragma unroll
    for (int nn = 0; nn < 4; ++nn) {
      int px = wc * 64 + nn * 16 + (l & 15);
      int slot = px * 4 + (kq ^ (px & 3));
      bf16x8 bh = lds[cg + 512 + slot];
#pragma unroll
      for (int m = 0; m < 4; ++m)
        acc[m][nn] = __builtin_amdgcn_mfma_f32_16x16x32_bf16(ah[m], bh, acc[m][nn], 0, 0, 0);
    }
    VMCNT0_BARRIER();                    // drain next-tile DMA, then barrier
  }

  // ---- epilogue: D col = lane&15 (px), row = (lane>>4)*4 + reg (fo)
  float bvv[4][4];
#pragma unroll
  for (int m = 0; m < 4; ++m)
#pragma unroll
    for (int r = 0; r < 4; ++r)
      bvv[m][r] = bias_ws[b * FOUT_C + wr * 64 + m * 16 + (l >> 4) * 4 + r];

#pragma unroll
  for (int m = 0; m < 4; ++m) {
#pragma unroll
    for (int nn = 0; nn < 4; ++nn) {
#pragma unroll
      for (int r = 0; r < 4; ++r) {
        int fo = wr * 64 + m * 16 + (l >> 4) * 4 + r;
        int p = pt * 128 + wc * 64 + nn * 16 + (l & 15);
        out[((size_t)b * FOUT_C + fo) * (HW * HW) + p] = acc[m][nn][r] + bvv[m][r];
      }
    }
  }
}

// ===========================================================================
// Fallback (proven fp32 path) in case ws_size < WS_NEED
// ===========================================================================
__global__ __launch_bounds__(256) void hyper_gemm_fb(
    const float* __restrict__ lat, const float* __restrict__ W,
    const float* __restrict__ bvec, float* __restrict__ kt,
    float* __restrict__ bias_ws) {
  int d = blockIdx.x * 256 + threadIdx.x;
  if (d >= NROWS) return;
  long n; int fo; bool isBias = (d >= KSZ);
  if (!isBias) {
    fo = d & 127; int rest = d >> 7; int tap = rest % 9; int fi = rest / 9;
    n = (long)fo * (FIN_C * KK * KK) + fi * (KK * KK) + tap;
  } else { fo = d - KSZ; n = KSZ + fo; }
  const float* wrow = W + n * LATD;
  float bv = bvec[n];
  float acc[NB];
#pragma unroll
  for (int b = 0; b < NB; ++b) acc[b] = bv;
#pragma unroll 2
  for (int k = 0; k < LATD; k += 4) {
    float4 wv = *reinterpret_cast<const float4*>(wrow + k);
#pragma unroll
    for (int b = 0; b < NB; ++b) {
      acc[b] += wv.x * lat[b * LATD + k] + wv.y * lat[b * LATD + k + 1] +
                wv.z * lat[b * LATD + k + 2] + wv.w * lat[b * LATD + k + 3];
    }
  }
  if (!isBias) {
#pragma unroll
    for (int b = 0; b < NB; ++b) kt[(long)b * KSZ + d] = acc[b];
  } else {
#pragma unroll
    for (int b = 0; b < NB; ++b) bias_ws[b * FOUT_C + fo] = acc[b];
  }
}

__global__ __launch_bounds__(64) void dyn_conv_fb(
    const float* __restrict__ x, const float* __restrict__ kt,
    const float* __restrict__ bias_ws, float* __restrict__ out) {
  const int h = blockIdx.x, b = blockIdx.y, fo0 = blockIdx.z * 32;
  const int w = threadIdx.x;
  const float* xb = x + (long)b * FIN_C * (HW * HW);
  const float* ktb = kt + (long)b * KSZ;
  const float* bb = bias_ws + b * FOUT_C + fo0;
  float acc[32];
#pragma unroll
  for (int j = 0; j < 32; ++j) acc[j] = bb[j];
  for (int fi = 0; fi < FIN_C; ++fi) {
    float xv[9];
    const float* xr = xb + fi * (HW * HW);
#pragma unroll
    for (int ky = 0; ky < 3; ++ky) {
      int hy = h + ky - 1;
      bool vr = (hy >= 0) && (hy < HW);
      const float* row = xr + hy * HW;
      xv[ky * 3 + 0] = (vr && w > 0) ? row[w - 1] : 0.f;
      xv[ky * 3 + 1] = vr ? row[w] : 0.f;
      xv[ky * 3 + 2] = (vr && w < 63) ? row[w + 1] : 0.f;
    }
    const float* wt = ktb + fi * (KK * KK * FOUT_C) + fo0;
#pragma unroll
    for (int t = 0; t < 9; ++t)
#pragma unroll
      for (int j = 0; j < 32; ++j) acc[j] += xv[t] * wt[t * FOUT_C + j];
  }
  float* ob = out + (((long)b * FOUT_C + fo0) * HW + h) * HW + w;
#pragma unroll
  for (int j = 0; j < 32; ++j) ob[(long)j * (HW * HW)] = acc[j];
}

// ---------------------------------------------------------------------------
extern "C" void kernel_launch(void* const* d_in, const int* in_sizes, int n_in,
                              void* d_out, int out_size, void* d_ws, size_t ws_size,
                              hipStream_t stream) {
  const float* x   = (const float*)d_in[0];
  const float* lat = (const float*)d_in[1];
  const float* W   = (const float*)d_in[2];
  const float* bv  = (const float*)d_in[3];
  float* out = (float*)d_out;
  char* ws = (char*)d_ws;

  if (ws_size >= WS_NEED) {
    unsigned short* Afh = (unsigned short*)(ws + AFH_OFF);
    unsigned short* xTh = (unsigned short*)(ws + XTH_OFF);
    float* ks_tmp = (float*)(ws + KST_OFF);
    float* bias_ws = (float*)(ws + BIAS_OFF);
    unsigned short* latFh = (unsigned short*)(ws + LATFH_OFF);

    latprep<<<dim3(1), dim3(256), 0, stream>>>(lat, latFh);
    hyper_gemm_mfma2<<<dim3(1153), dim3(256), 0, stream>>>(
        lat, W, bv, latFh, ks_tmp, bias_ws);
    reshuffle<<<dim3(576), dim3(256), 0, stream>>>(ks_tmp, Afh);
    prepass<<<dim3(XPAD, NB), dim3(256), 0, stream>>>(x, xTh);
    dyn_conv_mfma<<<dim3(32, NB), dim3(256), 0, stream>>>(Afh, xTh, bias_ws, out);
  } else {
    float* kt = (float*)d_ws;
    float* bias_ws = kt + (size_t)NB * KSZ;
    hyper_gemm_fb<<<dim3((NROWS + 255) / 256), dim3(256), 0, stream>>>(lat, W, bv, kt, bias_ws);
    dyn_conv_fb<<<dim3(HW, NB, 4), dim3(64), 0, stream>>>(x, kt, bias_ws, out);
  }
}